// Round 3
// baseline (211.879 us; speedup 1.0000x reference)
//
#include <hip/hip_runtime.h>
#include <math.h>

#define B_ 4
#define N_ 800
#define H_ 16

// ---- workspace layout (float indices) ----
#define WS_AP   0         // A' = h0*W1[:, :H] + b1      [4*800*16]
#define WS_BM   51200     // Bm = h0*W1[:, H:]           [4*800*16]
#define WS_P    102400    // P  = W3[:16,:]^T h0         [4*800*16]
#define WS_Q    153600    // Q  = W3[16:,:]^T h0         [4*800*16]
#define WS_D1   204800    // e - 2*c1                    [3200]
#define WS_D2   208000    // e - 2*c2                    [3200]
#define WS_AL   211200    // alpha per channel i         [800]
#define WS_BE   212000    // beta  per channel i         [800]
#define WS_SC   213072    // [0]=||b3||^2 [1]=sum(Wb)
#define WS_SS   213074    // sorted breakpoints          [16]
#define WS_WM   213090    // wm[k][h] = m*W2             [17*16]
#define WS_BMK  213362    // bm[k][h] = m*b2             [17*16]
#define WS_ABC  213634    // A,B,C,pad per interval      [17*4]
#define WS_PP   213702    // (PW,Pb) per (row,k)         [3200*17*2]
#define WS_QQ   322502    // (QW,Qb) per (row,k)         [3200*17*2]
#define WS_ACC  431302    // double loss accumulator (even float idx -> 8B aligned)
#define WS_TK   431304    // ticket counter (uint)

// ---------------- kernel 1: per-row prep + all weight-derived tables ----------------
__global__ __launch_bounds__(256) void prep_k(
    const float* __restrict__ x, const float* __restrict__ W_enc,
    const float* __restrict__ b_enc, const float* __restrict__ W1,
    const float* __restrict__ b1, const float* __restrict__ Wb,
    const float* __restrict__ b3, const float* __restrict__ W3,
    const float* __restrict__ W2, const float* __restrict__ b2,
    float* __restrict__ ws) {
  int t = threadIdx.x;
  if (blockIdx.x == 13) {               // weights-derived constants (whole block)
    __shared__ float sG[256], sR[16], sTB[16];
    __shared__ float sWM[272], sBMk[272];
    {
      int h = t >> 4, h2 = t & 15;
      float g = 0.f;
      #pragma unroll
      for (int o = 0; o < 32; ++o) g = fmaf(W3[o*16+h], W3[o*16+h2], g);
      sG[t] = g;
    }
    if (t < 16) {
      float r = 0.f;
      #pragma unroll
      for (int o = 0; o < 32; ++o) r = fmaf(W3[o*16+t], b3[o], r);
      sR[t] = r;
    }
    if (t == 0) {
      float bb3 = 0.f;
      for (int o = 0; o < 32; ++o) bb3 = fmaf(b3[o], b3[o], bb3);
      float wsum = 0.f;
      for (int k = 0; k < 16; ++k) wsum += Wb[k];
      ws[WS_SC + 0] = bb3;
      ws[WS_SC + 1] = wsum;
      *reinterpret_cast<double*>(ws + WS_ACC) = 0.0;      // ws re-poisoned each launch
      *reinterpret_cast<unsigned*>(ws + WS_TK) = 0u;

      // breakpoints of lrelu(z*W2+b2) mask, clamped to [-0.5,1.5]; sorted asc
      float tb[16];
      for (int hh = 0; hh < 16; ++hh) {
        float w = W2[hh], bv = b2[hh];
        float tt = (fabsf(w) > 1e-30f) ? (-bv / w) : ((bv > 0.f) ? -0.5f : 1.5f);
        tb[hh] = fminf(fmaxf(tt, -0.5f), 1.5f);
      }
      for (int a = 1; a < 16; ++a) {            // insertion sort, 16 elems
        float key = tb[a]; int c = a - 1;
        while (c >= 0 && tb[c] > key) { tb[c+1] = tb[c]; --c; }
        tb[c+1] = key;
      }
      for (int hh = 0; hh < 16; ++hh) { sTB[hh] = tb[hh]; ws[WS_SS + hh] = tb[hh]; }
    }
    __syncthreads();
    // per-interval masked weight vectors (parallel over 17*16 entries)
    for (int idx = t; idx < 272; idx += 256) {
      int k = idx >> 4, hh = idx & 15;
      float lo = (k == 0)  ? sTB[0]  - 1.f : sTB[k-1];
      float hi = (k == 16) ? sTB[15] + 1.f : sTB[k];
      float zr = 0.5f * (lo + hi);
      float v = fmaf(zr, W2[hh], b2[hh]);
      float m = (v > 0.f) ? 1.f : 0.01f;
      float wmv = m * W2[hh], bmv = m * b2[hh];
      sWM[idx] = wmv; sBMk[idx] = bmv;
      ws[WS_WM  + idx] = wmv;
      ws[WS_BMK + idx] = bmv;
    }
    __syncthreads();
    if (t < 17) {                       // per-interval quadratic coefficients
      int k = t;
      float A = 0.f, Bq = 0.f, Cq = 0.f, wr = 0.f, br = 0.f;
      #pragma unroll
      for (int h = 0; h < 16; ++h) {
        float wm = sWM[k*16 + h], bm = sBMk[k*16 + h];
        float gw = 0.f, gb = 0.f;
        #pragma unroll
        for (int h2 = 0; h2 < 16; ++h2) {
          float g = sG[h*16 + h2];
          gw = fmaf(g, sWM[k*16 + h2],  gw);
          gb = fmaf(g, sBMk[k*16 + h2], gb);
        }
        A  = fmaf(wm, gw, A);
        Bq = fmaf(wm, gb, Bq);
        Cq = fmaf(bm, gb, Cq);
        wr = fmaf(wm, sR[h], wr);
        br = fmaf(bm, sR[h], br);
      }
      ws[WS_ABC + k*4 + 0] = A;
      ws[WS_ABC + k*4 + 1] = 2.f * (Bq + wr);
      ws[WS_ABC + k*4 + 2] = Cq + 2.f * br;
      ws[WS_ABC + k*4 + 3] = 0.f;
    }
    return;
  }
  int row = blockIdx.x * 256 + t;       // row = b*N + n  (blocks 0..12 cover 3200)
  if (row >= B_ * N_) return;
  float xr[16];
  #pragma unroll
  for (int q = 0; q < 4; ++q) {
    float4 v = *reinterpret_cast<const float4*>(x + row*16 + q*4);
    xr[q*4+0] = v.x; xr[q*4+1] = v.y; xr[q*4+2] = v.z; xr[q*4+3] = v.w;
  }
  float h0[16];
  #pragma unroll
  for (int h = 0; h < 16; ++h) {        // node encoder + leaky relu
    float a = b_enc[h];
    #pragma unroll
    for (int k = 0; k < 16; ++k) a = fmaf(xr[k], W_enc[h*16+k], a);
    h0[h] = fmaxf(a, 0.01f * a);
  }
  #pragma unroll
  for (int h = 0; h < 16; ++h) {        // fc1 split halves (b1 folded into A')
    float a = b1[h], bm = 0.f;
    #pragma unroll
    for (int k = 0; k < 16; ++k) {
      a  = fmaf(h0[k], W1[h*32 + k],      a);
      bm = fmaf(h0[k], W1[h*32 + 16 + k], bm);
    }
    ws[WS_AP + row*16 + h] = a;
    ws[WS_BM + row*16 + h] = bm;
  }
  #pragma unroll
  for (int h = 0; h < 16; ++h) {        // loss cross-term projections
    float pp = 0.f, qq = 0.f;
    #pragma unroll
    for (int o = 0; o < 16; ++o) {
      pp = fmaf(W3[o*16 + h],        h0[o], pp);
      qq = fmaf(W3[(16+o)*16 + h],   h0[o], qq);
    }
    ws[WS_P + row*16 + h] = pp;
    ws[WS_Q + row*16 + h] = qq;
  }
  float c1 = 0.f, c2 = 0.f, e = 0.f;
  #pragma unroll
  for (int o = 0; o < 16; ++o) {
    c1 = fmaf(b3[o],      h0[o], c1);
    c2 = fmaf(b3[16+o],   h0[o], c2);
    e  = fmaf(h0[o],      h0[o], e);
  }
  ws[WS_D1 + row] = e - 2.f * c1;
  ws[WS_D2 + row] = e - 2.f * c2;
}

// ---------------- kernel 2: BN stats (blocks 0..799) + row projections (800..) ----------------
__global__ __launch_bounds__(256) void stats_proj_k(
    const float* __restrict__ bn_w, const float* __restrict__ bn_b,
    const float* __restrict__ bb, float* __restrict__ ws) {
  int t = threadIdx.x;
  if (blockIdx.x >= N_) {               // per-(row,interval) projections of P,Q
    int idx = (blockIdx.x - N_) * 256 + t;
    if (idx >= 3200 * 17) return;
    int row = idx / 17, k = idx - row * 17;
    const float* wm = ws + WS_WM  + k*16;
    const float* bm = ws + WS_BMK + k*16;
    const float* Pr = ws + WS_P + row*16;
    const float* Qr = ws + WS_Q + row*16;
    float pw = 0.f, pb = 0.f, qw = 0.f, qb = 0.f;
    #pragma unroll
    for (int h = 0; h < 16; ++h) {
      float p = Pr[h], q = Qr[h], w = wm[h], b = bm[h];
      pw = fmaf(w, p, pw); pb = fmaf(b, p, pb);
      qw = fmaf(w, q, qw); qb = fmaf(b, q, qb);
    }
    ws[WS_PP + idx*2 + 0] = pw;
    ws[WS_PP + idx*2 + 1] = pb;
    ws[WS_QQ + idx*2 + 0] = qw;
    ws[WS_QQ + idx*2 + 1] = qb;
    return;
  }
  int i = blockIdx.x;
  __shared__ float sA[4][16];
  if (t < 64) sA[t >> 4][t & 15] = ws[WS_AP + ((t >> 4)*N_ + i)*16 + (t & 15)];
  __syncthreads();
  float s = 0.f, s2 = 0.f;
  for (int b = 0; b < 4; ++b) {
    float a[16];
    #pragma unroll
    for (int h = 0; h < 16; ++h) a[h] = sA[b][h];
    for (int j = t; j < N_; j += 256) {
      const float4* bm4 = reinterpret_cast<const float4*>(ws + WS_BM + (b*N_ + j)*16);
      float4 v0 = bm4[0], v1 = bm4[1], v2 = bm4[2], v3 = bm4[3];
      float bm[16] = {v0.x,v0.y,v0.z,v0.w, v1.x,v1.y,v1.z,v1.w,
                      v2.x,v2.y,v2.z,v2.w, v3.x,v3.y,v3.z,v3.w};
      #pragma unroll
      for (int h = 0; h < 16; ++h) {
        float v = fmaxf(a[h] + bm[h], 0.f);
        s += v;
        s2 = fmaf(v, v, s2);
      }
    }
  }
  #pragma unroll
  for (int off = 32; off; off >>= 1) {
    s  += __shfl_down(s,  off);
    s2 += __shfl_down(s2, off);
  }
  __shared__ float rs[4], rs2[4];
  if ((t & 63) == 0) { rs[t >> 6] = s; rs2[t >> 6] = s2; }
  __syncthreads();
  if (t == 0) {
    s  = rs[0] + rs[1] + rs[2] + rs[3];
    s2 = rs2[0] + rs2[1] + rs2[2] + rs2[3];
    const float inv = 1.0f / (4.0f * N_ * 16.0f);      // 1/51200
    float mean = s * inv;
    float var  = s2 * inv - mean * mean;               // biased var
    float rstd = 1.0f / sqrtf(var + 1e-5f);
    float al = bn_w[i] * rstd;
    float wsum = ws[WS_SC + 1];
    float be = fmaf(-al * mean, wsum, fmaf(bn_b[i], wsum, bb[0]));
    ws[WS_AL + i] = al;
    ws[WS_BE + i] = be;
  }
}

// ---------------- kernel 3: main pair kernel (hw-trans math + fused finalize) ----------------
__global__ __launch_bounds__(256) void pair_k(
    const float* __restrict__ u, const float* __restrict__ Wb,
    float* __restrict__ ws, float* __restrict__ out,
    double* __restrict__ acc) {
  __shared__ __align__(16) float sAp[4][16][20], sBm[4][16][20];   // stride 20: conflict pad
  __shared__ __align__(16) float sPP[4][16][34], sQQ[4][16][34];   // (PW,Pb)/(QW,Qb) x 17 k
  __shared__ __align__(16) float4 sABC[17];
  __shared__ float sd1[4][16], sd2[4][16];
  __shared__ float sAl[16], sBe[16];
  __shared__ float red[4];
  __shared__ float sbb3;

  int t  = threadIdx.x;
  int bi = blockIdx.x % 50, bj = blockIdx.x / 50;
  int i0 = bi * 16, j0 = bj * 16;

  {
    int r = t >> 2, q = t & 3;          // 64 rows x 4 quads
    int b = r >> 4, l = r & 15;
    *reinterpret_cast<float4*>(&sAp[b][l][q*4]) =
        *reinterpret_cast<const float4*>(ws + WS_AP + ((b*N_ + i0 + l)*16) + q*4);
    *reinterpret_cast<float4*>(&sBm[b][l][q*4]) =
        *reinterpret_cast<const float4*>(ws + WS_BM + ((b*N_ + j0 + l)*16) + q*4);
  }
  for (int idx = t; idx < 4*16*34; idx += 256) {
    int b = idx / 544, rem = idx - b*544;
    int row = rem / 34, c = rem - row*34;
    sPP[b][row][c] = ws[WS_PP + ((b*N_ + i0 + row)*34) + c];
    sQQ[b][row][c] = ws[WS_QQ + ((b*N_ + j0 + row)*34) + c];
  }
  if (t < 68) reinterpret_cast<float*>(sABC)[t] = ws[WS_ABC + t];
  if (t < 64) {
    sd1[t >> 4][t & 15] = ws[WS_D1 + (t >> 4)*N_ + i0 + (t & 15)];
    sd2[t >> 4][t & 15] = ws[WS_D2 + (t >> 4)*N_ + j0 + (t & 15)];
  }
  if (t < 16) { sAl[t] = ws[WS_AL + i0 + t]; sBe[t] = ws[WS_BE + i0 + t]; }
  if (t == 0) sbb3 = ws[WS_SC + 0];

  float ssr[16];                         // uniform addresses: compiler scalarizes
  #pragma unroll
  for (int h = 0; h < 16; ++h) ssr[h] = ws[WS_SS + h];
  float wbr[16];
  #pragma unroll
  for (int h = 0; h < 16; ++h) wbr[h] = Wb[h];
  __syncthreads();

  int li = t >> 4, lj = t & 15;
  int i = i0 + li, j = j0 + lj;
  float alpha = sAl[li], beta = sBe[li];
  const float* up = u + i*N_ + j;
  float zsum = 0.f, Lacc = 0.f;

  #pragma unroll
  for (int b = 0; b < 4; ++b) {
    const float4 A0 = *reinterpret_cast<const float4*>(&sAp[b][li][0]);
    const float4 A1 = *reinterpret_cast<const float4*>(&sAp[b][li][4]);
    const float4 A2 = *reinterpret_cast<const float4*>(&sAp[b][li][8]);
    const float4 A3 = *reinterpret_cast<const float4*>(&sAp[b][li][12]);
    const float4 M0 = *reinterpret_cast<const float4*>(&sBm[b][lj][0]);
    const float4 M1 = *reinterpret_cast<const float4*>(&sBm[b][lj][4]);
    const float4 M2 = *reinterpret_cast<const float4*>(&sBm[b][lj][8]);
    const float4 M3 = *reinterpret_cast<const float4*>(&sBm[b][lj][12]);
    float S = 0.f, v;
    v = fmaxf(A0.x + M0.x, 0.f); S = fmaf(v, wbr[0],  S);
    v = fmaxf(A0.y + M0.y, 0.f); S = fmaf(v, wbr[1],  S);
    v = fmaxf(A0.z + M0.z, 0.f); S = fmaf(v, wbr[2],  S);
    v = fmaxf(A0.w + M0.w, 0.f); S = fmaf(v, wbr[3],  S);
    v = fmaxf(A1.x + M1.x, 0.f); S = fmaf(v, wbr[4],  S);
    v = fmaxf(A1.y + M1.y, 0.f); S = fmaf(v, wbr[5],  S);
    v = fmaxf(A1.z + M1.z, 0.f); S = fmaf(v, wbr[6],  S);
    v = fmaxf(A1.w + M1.w, 0.f); S = fmaf(v, wbr[7],  S);
    v = fmaxf(A2.x + M2.x, 0.f); S = fmaf(v, wbr[8],  S);
    v = fmaxf(A2.y + M2.y, 0.f); S = fmaf(v, wbr[9],  S);
    v = fmaxf(A2.z + M2.z, 0.f); S = fmaf(v, wbr[10], S);
    v = fmaxf(A2.w + M2.w, 0.f); S = fmaf(v, wbr[11], S);
    v = fmaxf(A3.x + M3.x, 0.f); S = fmaf(v, wbr[12], S);
    v = fmaxf(A3.y + M3.y, 0.f); S = fmaf(v, wbr[13], S);
    v = fmaxf(A3.z + M3.z, 0.f); S = fmaf(v, wbr[14], S);
    v = fmaxf(A3.w + M3.w, 0.f); S = fmaf(v, wbr[15], S);

    // logits = log(sigmoid(xl)) - log1p(-sigmoid(xl)) == xl  (exact identity,
    // matches reference saturation too). noise via hw v_log: 1-u is exact for
    // u>=0.5 (Sterbenz), <=1ulp rel below -> log(1-u) ~ log1p(-u) to ~1e-7.
    float xl = fmaf(alpha, S, beta);
    float uu = up[b * (N_ * N_)];
    float noise = __logf(uu) - __logf(1.0f - uu);
    float z = __fdividef(1.0f, 1.0f + __expf((xl + noise) * -5.0f));
    zsum += z;

    int kx = 0;                                // interval index: #breakpoints < z
    #pragma unroll
    for (int h = 0; h < 16; ++h) kx += (z > ssr[h]) ? 1 : 0;

    float4 abc = sABC[kx];
    float2 pp = *reinterpret_cast<const float2*>(&sPP[b][li][kx*2]);
    float2 qq = *reinterpret_cast<const float2*>(&sQQ[b][lj][kx*2]);
    float Lb = fmaf(abc.x, z*z, fmaf(abc.y, z, abc.z))
             - 2.f * fmaf(z, pp.x + qq.x, pp.y + qq.y)
             + sd1[b][li] + sd2[b][lj] + sbb3;
    Lacc += Lb;
  }

  out[i*N_ + j] = zsum * 0.25f;                // adj = mean over b

  #pragma unroll
  for (int off = 32; off; off >>= 1) Lacc += __shfl_down(Lacc, off);
  if ((t & 63) == 0) red[t >> 6] = Lacc;
  __syncthreads();
  if (t == 0) {
    atomicAdd(acc, (double)(red[0] + red[1] + red[2] + red[3]));
    __threadfence();                           // release our acc add
    unsigned old = atomicAdd(reinterpret_cast<unsigned*>(ws + WS_TK), 1u);
    if (old == 2499u) {                        // last block finalizes the loss
      double v = atomicAdd(acc, 0.0);          // coherent read incl. all adds
      out[N_ * N_] = (float)(v * (1.0 / (4.0 * 800.0 * 800.0 * 32.0)));
    }
  }
}

extern "C" void kernel_launch(void* const* d_in, const int* in_sizes, int n_in,
                              void* d_out, int out_size, void* d_ws, size_t ws_size,
                              hipStream_t stream) {
  const float* x     = (const float*)d_in[0];
  const float* u     = (const float*)d_in[1];
  const float* W_enc = (const float*)d_in[2];
  const float* b_enc = (const float*)d_in[3];
  const float* W1    = (const float*)d_in[4];
  const float* b1    = (const float*)d_in[5];
  const float* Wb    = (const float*)d_in[6];
  const float* bb    = (const float*)d_in[7];
  // d_in[8..11] = Wmu, bmu, Wlv, blv — dead code in the reference
  const float* bn_w  = (const float*)d_in[12];
  const float* bn_b  = (const float*)d_in[13];
  const float* W2    = (const float*)d_in[14];
  const float* b2    = (const float*)d_in[15];
  const float* W3    = (const float*)d_in[16];
  const float* b3    = (const float*)d_in[17];

  float*  out = (float*)d_out;
  float*  ws  = (float*)d_ws;
  double* acc = (double*)(ws + WS_ACC);

  prep_k      <<<14,       256, 0, stream>>>(x, W_enc, b_enc, W1, b1, Wb, b3, W3, W2, b2, ws);
  stats_proj_k<<<N_ + 213, 256, 0, stream>>>(bn_w, bn_b, bb, ws);
  pair_k      <<<2500,     256, 0, stream>>>(u, Wb, ws, out, acc);
}

// Round 4
// 144.059 us; speedup vs baseline: 1.4708x; 1.4708x over previous
//
#include <hip/hip_runtime.h>
#include <math.h>

#define B_ 4
#define N_ 800
#define H_ 16

// ---- workspace layout (float indices) ----
#define WS_AP   0         // A' = h0*W1[:, :H] + b1      [4*800*16]
#define WS_BM   51200     // Bm = h0*W1[:, H:]           [4*800*16]
#define WS_P    102400    // P  = W3[:16,:]^T h0         [4*800*16]
#define WS_Q    153600    // Q  = W3[16:,:]^T h0         [4*800*16]
#define WS_D1   204800    // e - 2*c1                    [3200]
#define WS_D2   208000    // e - 2*c2                    [3200]
#define WS_S    211200    // BN sum  per channel i       [800]
#define WS_S2   212000    // BN sum2 per channel i       [800]
#define WS_SC   213072    // [0]=||b3||^2 [1]=sum(Wb)
#define WS_SS   213074    // sorted breakpoints          [16]
#define WS_WM   213090    // wm[k][h] = m*W2             [17*16]
#define WS_BMK  213362    // bm[k][h] = m*b2             [17*16]
#define WS_ABC  213634    // A,B,C,pad per interval      [17*4]
#define WS_PP   213702    // (PW,Pb) per (row,k)         [3200*17*2]
#define WS_QQ   322502    // (QW,Qb) per (row,k)         [3200*17*2]
#define WS_ACC  431302    // double loss accumulator (even float idx -> 8B aligned)

// ---------------- kernel 1: per-row prep + weight tables + ws zeroing ----------------
__global__ __launch_bounds__(256) void prep_k(
    const float* __restrict__ x, const float* __restrict__ W_enc,
    const float* __restrict__ b_enc, const float* __restrict__ W1,
    const float* __restrict__ b1, const float* __restrict__ Wb,
    const float* __restrict__ b3, const float* __restrict__ W3,
    const float* __restrict__ W2, const float* __restrict__ b2,
    float* __restrict__ ws) {
  int t = threadIdx.x;
  if (blockIdx.x == 14) {               // zero the BN accumulators (ws is poisoned)
    for (int i = t; i < 1600; i += 256) ws[WS_S + i] = 0.f;
    return;
  }
  if (blockIdx.x == 13) {               // weights-derived constants (whole block)
    __shared__ float sG[256], sR[16], sTB[16];
    __shared__ float sWM[272], sBMk[272];
    {
      int h = t >> 4, h2 = t & 15;
      float g = 0.f;
      #pragma unroll
      for (int o = 0; o < 32; ++o) g = fmaf(W3[o*16+h], W3[o*16+h2], g);
      sG[t] = g;
    }
    if (t < 16) {
      float r = 0.f;
      #pragma unroll
      for (int o = 0; o < 32; ++o) r = fmaf(W3[o*16+t], b3[o], r);
      sR[t] = r;
    }
    if (t == 0) {
      float bb3 = 0.f;
      for (int o = 0; o < 32; ++o) bb3 = fmaf(b3[o], b3[o], bb3);
      float wsum = 0.f;
      for (int k = 0; k < 16; ++k) wsum += Wb[k];
      ws[WS_SC + 0] = bb3;
      ws[WS_SC + 1] = wsum;
      *reinterpret_cast<double*>(ws + WS_ACC) = 0.0;

      float tb[16];                      // lrelu-mask breakpoints, clamp [-0.5,1.5]
      for (int hh = 0; hh < 16; ++hh) {
        float w = W2[hh], bv = b2[hh];
        float tt = (fabsf(w) > 1e-30f) ? (-bv / w) : ((bv > 0.f) ? -0.5f : 1.5f);
        tb[hh] = fminf(fmaxf(tt, -0.5f), 1.5f);
      }
      for (int a = 1; a < 16; ++a) {     // insertion sort, 16 elems
        float key = tb[a]; int c = a - 1;
        while (c >= 0 && tb[c] > key) { tb[c+1] = tb[c]; --c; }
        tb[c+1] = key;
      }
      for (int hh = 0; hh < 16; ++hh) { sTB[hh] = tb[hh]; ws[WS_SS + hh] = tb[hh]; }
    }
    __syncthreads();
    for (int idx = t; idx < 272; idx += 256) {   // per-interval masked weights
      int k = idx >> 4, hh = idx & 15;
      float lo = (k == 0)  ? sTB[0]  - 1.f : sTB[k-1];
      float hi = (k == 16) ? sTB[15] + 1.f : sTB[k];
      float zr = 0.5f * (lo + hi);
      float v = fmaf(zr, W2[hh], b2[hh]);
      float m = (v > 0.f) ? 1.f : 0.01f;
      float wmv = m * W2[hh], bmv = m * b2[hh];
      sWM[idx] = wmv; sBMk[idx] = bmv;
      ws[WS_WM  + idx] = wmv;
      ws[WS_BMK + idx] = bmv;
    }
    __syncthreads();
    if (t < 17) {                        // per-interval quadratic coefficients
      int k = t;
      float A = 0.f, Bq = 0.f, Cq = 0.f, wr = 0.f, br = 0.f;
      #pragma unroll
      for (int h = 0; h < 16; ++h) {
        float wm = sWM[k*16 + h], bm = sBMk[k*16 + h];
        float gw = 0.f, gb = 0.f;
        #pragma unroll
        for (int h2 = 0; h2 < 16; ++h2) {
          float g = sG[h*16 + h2];
          gw = fmaf(g, sWM[k*16 + h2],  gw);
          gb = fmaf(g, sBMk[k*16 + h2], gb);
        }
        A  = fmaf(wm, gw, A);
        Bq = fmaf(wm, gb, Bq);
        Cq = fmaf(bm, gb, Cq);
        wr = fmaf(wm, sR[h], wr);
        br = fmaf(bm, sR[h], br);
      }
      ws[WS_ABC + k*4 + 0] = A;
      ws[WS_ABC + k*4 + 1] = 2.f * (Bq + wr);
      ws[WS_ABC + k*4 + 2] = Cq + 2.f * br;
      ws[WS_ABC + k*4 + 3] = 0.f;
    }
    return;
  }
  int row = blockIdx.x * 256 + t;        // rows, blocks 0..12
  if (row >= B_ * N_) return;
  float xr[16];
  #pragma unroll
  for (int q = 0; q < 4; ++q) {
    float4 v = *reinterpret_cast<const float4*>(x + row*16 + q*4);
    xr[q*4+0] = v.x; xr[q*4+1] = v.y; xr[q*4+2] = v.z; xr[q*4+3] = v.w;
  }
  float h0[16];
  #pragma unroll
  for (int h = 0; h < 16; ++h) {
    float a = b_enc[h];
    #pragma unroll
    for (int k = 0; k < 16; ++k) a = fmaf(xr[k], W_enc[h*16+k], a);
    h0[h] = fmaxf(a, 0.01f * a);
  }
  #pragma unroll
  for (int h = 0; h < 16; ++h) {
    float a = b1[h], bm = 0.f;
    #pragma unroll
    for (int k = 0; k < 16; ++k) {
      a  = fmaf(h0[k], W1[h*32 + k],      a);
      bm = fmaf(h0[k], W1[h*32 + 16 + k], bm);
    }
    ws[WS_AP + row*16 + h] = a;
    ws[WS_BM + row*16 + h] = bm;
  }
  #pragma unroll
  for (int h = 0; h < 16; ++h) {
    float pp = 0.f, qq = 0.f;
    #pragma unroll
    for (int o = 0; o < 16; ++o) {
      pp = fmaf(W3[o*16 + h],      h0[o], pp);
      qq = fmaf(W3[(16+o)*16 + h], h0[o], qq);
    }
    ws[WS_P + row*16 + h] = pp;
    ws[WS_Q + row*16 + h] = qq;
  }
  float c1 = 0.f, c2 = 0.f, e = 0.f;
  #pragma unroll
  for (int o = 0; o < 16; ++o) {
    c1 = fmaf(b3[o],    h0[o], c1);
    c2 = fmaf(b3[16+o], h0[o], c2);
    e  = fmaf(h0[o],    h0[o], e);
  }
  ws[WS_D1 + row] = e - 2.f * c1;
  ws[WS_D2 + row] = e - 2.f * c2;
}

// ---------------- kernel 2: BN partial sums (0..199) + row projections (200..) ----------------
__global__ __launch_bounds__(256) void stats_proj_k(float* __restrict__ ws) {
  int t = threadIdx.x;
  int blk = blockIdx.x;
  if (blk >= 200) {                      // per-(row,interval) projections of P,Q
    int idx = (blk - 200) * 256 + t;
    if (idx >= 3200 * 17) return;
    int row = idx / 17, k = idx - row * 17;
    const float* wm = ws + WS_WM  + k*16;
    const float* bm = ws + WS_BMK + k*16;
    const float* Pr = ws + WS_P + row*16;
    const float* Qr = ws + WS_Q + row*16;
    float pw = 0.f, pb = 0.f, qw = 0.f, qb = 0.f;
    #pragma unroll
    for (int h = 0; h < 16; ++h) {
      float p = Pr[h], q = Qr[h], w = wm[h], b = bm[h];
      pw = fmaf(w, p, pw); pb = fmaf(b, p, pb);
      qw = fmaf(w, q, qw); qb = fmaf(b, q, qb);
    }
    ws[WS_PP + idx*2 + 0] = pw;
    ws[WS_PP + idx*2 + 1] = pb;
    ws[WS_QQ + idx*2 + 0] = qw;
    ws[WS_QQ + idx*2 + 1] = qb;
    return;
  }
  // BN partial: block = (i-tile of 16) x (j-slice of 200)
  int it = blk >> 2, js = blk & 3;
  int i0 = it * 16, jbase = js * 200;
  __shared__ __align__(16) float sBMs[4][200][20];   // stride 20: conflict-free b128
  __shared__ __align__(16) float sAt[4][16][16];
  for (int idx = t; idx < 3200; idx += 256) {        // 3200 float4 = 4b x 200r x 4q
    int r = idx >> 2, q = idx & 3;
    int b = r / 200, l = r - b*200;
    *reinterpret_cast<float4*>(&sBMs[b][l][q*4]) =
        *reinterpret_cast<const float4*>(ws + WS_BM + (b*N_ + jbase + l)*16 + q*4);
  }
  {
    int b = t >> 6, r = t & 63;                      // 256 float4 for the A tile
    reinterpret_cast<float4*>(&sAt[0][0][0])[t] =
        *reinterpret_cast<const float4*>(ws + WS_AP + (b*N_ + i0)*16 + r*4);
  }
  __syncthreads();
  int il = t >> 4, jt = t & 15;
  float a[4][16];
  #pragma unroll
  for (int b = 0; b < 4; ++b)
    #pragma unroll
    for (int h = 0; h < 16; ++h) a[b][h] = sAt[b][il][h];   // LDS broadcast
  float s = 0.f, s2 = 0.f;
  for (int jj = 0; jj < 13; ++jj) {
    int j = jt + jj*16;
    if (j >= 200) break;
    #pragma unroll
    for (int b = 0; b < 4; ++b) {
      #pragma unroll
      for (int q = 0; q < 4; ++q) {
        float4 bm = *reinterpret_cast<const float4*>(&sBMs[b][j][q*4]);
        float v;
        v = fmaxf(a[b][q*4+0] + bm.x, 0.f); s += v; s2 = fmaf(v, v, s2);
        v = fmaxf(a[b][q*4+1] + bm.y, 0.f); s += v; s2 = fmaf(v, v, s2);
        v = fmaxf(a[b][q*4+2] + bm.z, 0.f); s += v; s2 = fmaf(v, v, s2);
        v = fmaxf(a[b][q*4+3] + bm.w, 0.f); s += v; s2 = fmaf(v, v, s2);
      }
    }
  }
  #pragma unroll
  for (int off = 8; off; off >>= 1) {                // reduce within 16-lane group
    s  += __shfl_down(s,  off, 16);
    s2 += __shfl_down(s2, off, 16);
  }
  if (jt == 0) {
    atomicAdd(ws + WS_S  + i0 + il, s);
    atomicAdd(ws + WS_S2 + i0 + il, s2);
  }
}

// ---------------- kernel 3: main 32x32 pair kernel ----------------
__global__ __launch_bounds__(256) void pair_k(
    const float* __restrict__ u, const float* __restrict__ Wb,
    const float* __restrict__ bn_w, const float* __restrict__ bn_b,
    const float* __restrict__ bb, const float* __restrict__ ws,
    float* __restrict__ out, double* __restrict__ acc) {
  __shared__ __align__(16) float sAp[4][32][16];   // b128 broadcast reads: no pad needed
  __shared__ __align__(16) float sBm[4][32][17];   // stride 17: scalar reads conflict-free
  __shared__ __align__(16) float sPP[4][32][34], sQQ[4][32][34];
  __shared__ __align__(16) float4 sABC[17];
  __shared__ float sd1[4][32], sd2[4][32];
  __shared__ float sAl[32], sBe[32];
  __shared__ float red[4];
  __shared__ float sbb3;

  int t  = threadIdx.x;
  int bi = blockIdx.x % 25, bj = blockIdx.x / 25;
  int i0 = bi * 32, j0 = bj * 32;
  int li = t >> 4, lj = t & 15;

  // ---- u prefetch: 16 independent HBM loads in flight during LDS staging ----
  float ur[16];
  #pragma unroll
  for (int b = 0; b < 4; ++b)
    #pragma unroll
    for (int di = 0; di < 2; ++di)
      #pragma unroll
      for (int dj = 0; dj < 2; ++dj)
        ur[b*4 + di*2 + dj] = u[(b*N_ + i0 + li + di*16)*N_ + j0 + lj + dj*16];

  // ---- staging (linear bulk copies from L2-resident ws) ----
  {
    float4* dAp = reinterpret_cast<float4*>(&sAp[0][0][0]);
    for (int idx = t; idx < 512; idx += 256) {       // 4b x 128 f4, LDS layout == global
      int b = idx >> 7, r = idx & 127;
      dAp[idx] = *reinterpret_cast<const float4*>(ws + WS_AP + (b*N_ + i0)*16 + r*4);
    }
    for (int idx = t; idx < 2048; idx += 256) {      // sBm stride-17 scatter
      int b = idx >> 9, r = idx & 511;
      int l = r >> 4, h = r & 15;
      sBm[b][l][h] = ws[WS_BM + (b*N_ + j0 + l)*16 + h];
    }
    float2* dPP = reinterpret_cast<float2*>(&sPP[0][0][0]);
    float2* dQQ = reinterpret_cast<float2*>(&sQQ[0][0][0]);
    for (int idx = t; idx < 2176; idx += 256) {      // 4b x 544 f2 each, layouts match
      int b = idx / 544, r = idx - b*544;
      dPP[idx] = *reinterpret_cast<const float2*>(ws + WS_PP + (b*N_ + i0)*34 + r*2);
      dQQ[idx] = *reinterpret_cast<const float2*>(ws + WS_QQ + (b*N_ + j0)*34 + r*2);
    }
  }
  if (t < 68) reinterpret_cast<float*>(sABC)[t] = ws[WS_ABC + t];
  if (t < 128) {
    sd1[t >> 5][t & 31] = ws[WS_D1 + (t >> 5)*N_ + i0 + (t & 31)];
    sd2[t >> 5][t & 31] = ws[WS_D2 + (t >> 5)*N_ + j0 + (t & 31)];
  }
  if (t < 32) {                                      // BN finalize, folded in
    float s = ws[WS_S + i0 + t], s2 = ws[WS_S2 + i0 + t];
    const float inv = 1.0f / 51200.0f;
    float mean = s * inv;
    float var  = s2 * inv - mean * mean;
    float rstd = 1.0f / sqrtf(var + 1e-5f);
    float al = bn_w[i0 + t] * rstd;
    float wsum = ws[WS_SC + 1];
    sAl[t] = al;
    sBe[t] = fmaf(-al * mean, wsum, fmaf(bn_b[i0 + t], wsum, bb[0]));
  }
  if (t == 0) sbb3 = ws[WS_SC + 0];
  float ssr[16], wbr[16];                            // uniform -> SGPRs
  #pragma unroll
  for (int h = 0; h < 16; ++h) ssr[h] = ws[WS_SS + h];
  #pragma unroll
  for (int h = 0; h < 16; ++h) wbr[h] = Wb[h];
  __syncthreads();

  float al0 = sAl[li], be0 = sBe[li], al1 = sAl[li+16], be1 = sBe[li+16];
  float zsum[4] = {0.f, 0.f, 0.f, 0.f};
  float Lacc = 0.f;

  #pragma unroll
  for (int b = 0; b < 4; ++b) {
    float Af[2][16], Mf[2][16];
    #pragma unroll
    for (int d = 0; d < 2; ++d) {
      #pragma unroll
      for (int q = 0; q < 4; ++q) {                  // b128 broadcast (2-way: free)
        float4 va = *reinterpret_cast<const float4*>(&sAp[b][li + d*16][q*4]);
        Af[d][q*4+0] = va.x; Af[d][q*4+1] = va.y; Af[d][q*4+2] = va.z; Af[d][q*4+3] = va.w;
      }
      #pragma unroll
      for (int h = 0; h < 16; ++h)                   // stride-17 scalar: conflict-free
        Mf[d][h] = sBm[b][lj + d*16][h];
    }
    #pragma unroll
    for (int di = 0; di < 2; ++di) {
      #pragma unroll
      for (int dj = 0; dj < 2; ++dj) {
        float S = 0.f;
        #pragma unroll
        for (int h = 0; h < 16; ++h) {
          float v = fmaxf(Af[di][h] + Mf[dj][h], 0.f);
          S = fmaf(v, wbr[h], S);
        }
        // logits == xl exactly (log(sigmoid x) - log1p(-sigmoid x) == x)
        float xl = fmaf(di ? al1 : al0, S, di ? be1 : be0);
        float uu = ur[b*4 + di*2 + dj];
        float noise = __logf(uu) - __logf(1.0f - uu);
        float z = __fdividef(1.0f, 1.0f + __expf((xl + noise) * -5.0f));
        zsum[di*2 + dj] += z;
        int kx = 0;
        #pragma unroll
        for (int h = 0; h < 16; ++h) kx += (z > ssr[h]) ? 1 : 0;
        float4 abc = sABC[kx];
        float2 pp = *reinterpret_cast<const float2*>(&sPP[b][li + di*16][kx*2]);
        float2 qq = *reinterpret_cast<const float2*>(&sQQ[b][lj + dj*16][kx*2]);
        Lacc += fmaf(abc.x, z*z, fmaf(abc.y, z, abc.z))
              - 2.f * fmaf(z, pp.x + qq.x, pp.y + qq.y)
              + sd1[b][li + di*16] + sd2[b][lj + dj*16] + sbb3;
      }
    }
  }

  #pragma unroll
  for (int di = 0; di < 2; ++di)
    #pragma unroll
    for (int dj = 0; dj < 2; ++dj)
      out[(i0 + li + di*16)*N_ + j0 + lj + dj*16] = zsum[di*2 + dj] * 0.25f;

  #pragma unroll
  for (int off = 32; off; off >>= 1) Lacc += __shfl_down(Lacc, off);
  if ((t & 63) == 0) red[t >> 6] = Lacc;
  __syncthreads();
  if (t == 0) atomicAdd(acc, (double)(red[0] + red[1] + red[2] + red[3]));
}

// ---------------- kernel 4: finalize loss ----------------
__global__ void fin_k(const double* __restrict__ acc, float* __restrict__ out) {
  out[N_ * N_] = (float)(*acc * (1.0 / (4.0 * 800.0 * 800.0 * 32.0)));
}

extern "C" void kernel_launch(void* const* d_in, const int* in_sizes, int n_in,
                              void* d_out, int out_size, void* d_ws, size_t ws_size,
                              hipStream_t stream) {
  const float* x     = (const float*)d_in[0];
  const float* u     = (const float*)d_in[1];
  const float* W_enc = (const float*)d_in[2];
  const float* b_enc = (const float*)d_in[3];
  const float* W1    = (const float*)d_in[4];
  const float* b1    = (const float*)d_in[5];
  const float* Wb    = (const float*)d_in[6];
  const float* bb    = (const float*)d_in[7];
  // d_in[8..11] = Wmu, bmu, Wlv, blv — dead code in the reference
  const float* bn_w  = (const float*)d_in[12];
  const float* bn_b  = (const float*)d_in[13];
  const float* W2    = (const float*)d_in[14];
  const float* b2    = (const float*)d_in[15];
  const float* W3    = (const float*)d_in[16];
  const float* b3    = (const float*)d_in[17];

  float*  out = (float*)d_out;
  float*  ws  = (float*)d_ws;
  double* acc = (double*)(ws + WS_ACC);

  prep_k      <<<15,  256, 0, stream>>>(x, W_enc, b_enc, W1, b1, Wb, b3, W3, W2, b2, ws);
  stats_proj_k<<<413, 256, 0, stream>>>(ws);
  pair_k      <<<625, 256, 0, stream>>>(u, Wb, bn_w, bn_b, bb, ws, out, acc);
  fin_k       <<<1,   1,   0, stream>>>(acc, out);
}